// Round 1
// baseline (911.832 us; speedup 1.0000x reference)
//
#include <hip/hip_runtime.h>

// ---------------------------------------------------------------------------
// BeliefStateWrapper: gather(fi,bi) -> Linear(1024->512)+LeakyReLU ->
// Linear(512->64000) -> per-branch log_softmax NLL -> weighted mean (scalar).
// Strategy: bf16 MFMA GEMMs; logsumexp fused into GEMM2 epilogue (no max
// subtraction needed: |logit| ~ 0.2, exp is fp32-safe); label logits via
// separate dot-product kernel; final reduce to scalar.
// ---------------------------------------------------------------------------

typedef __bf16 bf16x8 __attribute__((ext_vector_type(8)));
typedef __bf16 bf16x4 __attribute__((ext_vector_type(4)));
typedef float f32x4  __attribute__((ext_vector_type(4)));

#define MFMA16(a, b, c) __builtin_amdgcn_mfma_f32_16x16x32_bf16(a, b, c, 0, 0, 0)

static constexpr int Bsz   = 2;
static constexpr int L     = 512;
static constexpr int D     = 512;
static constexpr int V     = 32000;
static constexpr int K1    = 2 * D;      // 1024
static constexpr int N1    = D;          // 512
static constexpr int K2    = D;          // 512
static constexpr int N2    = 2 * V;      // 64000

// ---------------------------------------------------------------------------
// Kernel 1: gather + cast to bf16.  A1[m][k], m = b*N + n, k in [0,1024):
//   k < 512 -> fwd[b, fi[n], k]; else bwd[b, bi[n], k-512].  Pad rows = 0.
// ---------------------------------------------------------------------------
__global__ void gather_cast_kernel(const float* __restrict__ fwd,
                                   const float* __restrict__ bwd,
                                   const int* __restrict__ fi,
                                   const int* __restrict__ bi,
                                   __bf16* __restrict__ A1,
                                   int N, int M, int Mpad) {
    int t = blockIdx.x * 256 + threadIdx.x;          // one thread = 8 elems
    int total = Mpad * (K1 / 8);
    if (t >= total) return;
    int m  = t >> 7;              // / (1024/8)
    int c8 = (t & 127) * 8;
    bf16x8 out;
    if (m < M) {
        int b = m / N;
        int n = m - b * N;
        const float* src;
        if (c8 < D) src = fwd + ((size_t)(b * L + fi[n])) * D + c8;
        else        src = bwd + ((size_t)(b * L + bi[n])) * D + (c8 - D);
        float4 v0 = *(const float4*)(src);
        float4 v1 = *(const float4*)(src + 4);
        out[0] = (__bf16)v0.x; out[1] = (__bf16)v0.y;
        out[2] = (__bf16)v0.z; out[3] = (__bf16)v0.w;
        out[4] = (__bf16)v1.x; out[5] = (__bf16)v1.y;
        out[6] = (__bf16)v1.z; out[7] = (__bf16)v1.w;
    } else {
        for (int j = 0; j < 8; j++) out[j] = (__bf16)0.0f;
    }
    *(bf16x8*)(A1 + (size_t)m * K1 + c8) = out;
}

// ---------------------------------------------------------------------------
// Kernel 2: transpose + cast fp32 [K][Nn] -> bf16 [Nn][K] (k-contiguous rows).
// ---------------------------------------------------------------------------
__global__ void transpose_cast_kernel(const float* __restrict__ src,
                                      __bf16* __restrict__ dst,
                                      int K, int Nn) {
    __shared__ __align__(16) __bf16 tile[64][68];
    int t  = threadIdx.x;
    int tx = t & 15, ty = t >> 4;
    int n0 = blockIdx.x * 64, k0 = blockIdx.y * 64;
    for (int i = 0; i < 4; i++) {
        int k = k0 + ty + 16 * i;
        float4 v = *(const float4*)(src + (size_t)k * Nn + n0 + tx * 4);
        tile[tx * 4 + 0][ty + 16 * i] = (__bf16)v.x;
        tile[tx * 4 + 1][ty + 16 * i] = (__bf16)v.y;
        tile[tx * 4 + 2][ty + 16 * i] = (__bf16)v.z;
        tile[tx * 4 + 3][ty + 16 * i] = (__bf16)v.w;
    }
    __syncthreads();
    for (int i = 0; i < 4; i++) {
        int n = n0 + ty + 16 * i;
        bf16x4 o;
        o[0] = tile[ty + 16 * i][tx * 4 + 0];
        o[1] = tile[ty + 16 * i][tx * 4 + 1];
        o[2] = tile[ty + 16 * i][tx * 4 + 2];
        o[3] = tile[ty + 16 * i][tx * 4 + 3];
        *(bf16x4*)(dst + (size_t)n * K + k0 + tx * 4) = o;
    }
}

// ---------------------------------------------------------------------------
// GEMM1: H = leaky_relu(A1 @ W1 + b1), C stored bf16 [Mpad][512].
// 128x128 block tile, 4 waves (2x2), each wave 64x64 via 4x4 of 16x16x32 MFMA.
// A [*,K] k-contiguous; Bt [n][k] k-contiguous (pre-transposed).
// ---------------------------------------------------------------------------
__global__ __launch_bounds__(256) void gemm1_kernel(
        const __bf16* __restrict__ A, const __bf16* __restrict__ Bt,
        const float* __restrict__ bias, __bf16* __restrict__ H, int K) {
    __shared__ __align__(16) __bf16 At[128][40];
    __shared__ __align__(16) __bf16 Bl[128][40];
    const int t = threadIdx.x;
    const int m0 = blockIdx.y * 128, n0 = blockIdx.x * 128;
    const int srow = t >> 2, schunk = (t & 3) * 8;
    const int wave = t >> 6, lane = t & 63;
    const int wrow = (wave >> 1) * 64, wcol = (wave & 1) * 64;
    const int q = lane >> 4, ln = lane & 15;

    f32x4 acc[4][4] = {};
    for (int k0 = 0; k0 < K; k0 += 32) {
        __syncthreads();
        *(bf16x8*)&At[srow][schunk]      = *(const bf16x8*)(A  + (size_t)(m0 + srow)      * K + k0 + schunk);
        *(bf16x8*)&At[srow + 64][schunk] = *(const bf16x8*)(A  + (size_t)(m0 + srow + 64) * K + k0 + schunk);
        *(bf16x8*)&Bl[srow][schunk]      = *(const bf16x8*)(Bt + (size_t)(n0 + srow)      * K + k0 + schunk);
        *(bf16x8*)&Bl[srow + 64][schunk] = *(const bf16x8*)(Bt + (size_t)(n0 + srow + 64) * K + k0 + schunk);
        __syncthreads();
        bf16x8 af[4], bfr[4];
        for (int i = 0; i < 4; i++) af[i]  = *(const bf16x8*)&At[wrow + i * 16 + ln][q * 8];
        for (int i = 0; i < 4; i++) bfr[i] = *(const bf16x8*)&Bl[wcol + i * 16 + ln][q * 8];
        for (int mi = 0; mi < 4; mi++)
            for (int ni = 0; ni < 4; ni++)
                acc[mi][ni] = MFMA16(af[mi], bfr[ni], acc[mi][ni]);
    }
    // epilogue: + bias, leaky_relu(0.01), store bf16
    for (int ni = 0; ni < 4; ni++) {
        int gcol = n0 + wcol + ni * 16 + ln;
        float bv = bias[gcol];
        for (int mi = 0; mi < 4; mi++)
            for (int r = 0; r < 4; r++) {
                int gm = m0 + wrow + mi * 16 + q * 4 + r;
                float v = acc[mi][ni][r] + bv;
                v = v > 0.0f ? v : 0.01f * v;
                H[(size_t)gm * N1 + gcol] = (__bf16)v;
            }
    }
}

// ---------------------------------------------------------------------------
// GEMM2: logits = H @ W2 + b2 ; epilogue computes sum(exp(logit)) per row per
// branch (no max subtraction; logits are ~N(0,0.2)) via in-wave shuffle
// reduction + atomicAdd into sumexp[m*2+branch].
// ---------------------------------------------------------------------------
__global__ __launch_bounds__(256) void gemm2_kernel(
        const __bf16* __restrict__ A, const __bf16* __restrict__ Bt,
        const float* __restrict__ b2, float* __restrict__ sumexp, int K) {
    __shared__ __align__(16) __bf16 At[128][40];
    __shared__ __align__(16) __bf16 Bl[128][40];
    const int t = threadIdx.x;
    const int m0 = blockIdx.y * 128, n0 = blockIdx.x * 128;
    const int srow = t >> 2, schunk = (t & 3) * 8;
    const int wave = t >> 6, lane = t & 63;
    const int wrow = (wave >> 1) * 64, wcol = (wave & 1) * 64;
    const int q = lane >> 4, ln = lane & 15;

    f32x4 acc[4][4] = {};
    for (int k0 = 0; k0 < K; k0 += 32) {
        __syncthreads();
        *(bf16x8*)&At[srow][schunk]      = *(const bf16x8*)(A  + (size_t)(m0 + srow)      * K + k0 + schunk);
        *(bf16x8*)&At[srow + 64][schunk] = *(const bf16x8*)(A  + (size_t)(m0 + srow + 64) * K + k0 + schunk);
        *(bf16x8*)&Bl[srow][schunk]      = *(const bf16x8*)(Bt + (size_t)(n0 + srow)      * K + k0 + schunk);
        *(bf16x8*)&Bl[srow + 64][schunk] = *(const bf16x8*)(Bt + (size_t)(n0 + srow + 64) * K + k0 + schunk);
        __syncthreads();
        bf16x8 af[4], bfr[4];
        for (int i = 0; i < 4; i++) af[i]  = *(const bf16x8*)&At[wrow + i * 16 + ln][q * 8];
        for (int i = 0; i < 4; i++) bfr[i] = *(const bf16x8*)&Bl[wcol + i * 16 + ln][q * 8];
        for (int mi = 0; mi < 4; mi++)
            for (int ni = 0; ni < 4; ni++)
                acc[mi][ni] = MFMA16(af[mi], bfr[ni], acc[mi][ni]);
    }
    // epilogue: exp + row-sum.  128 | 32000 so a block never straddles branches.
    const int branch = n0 / V;
    float rowsum[4][4];
    for (int mi = 0; mi < 4; mi++)
        for (int r = 0; r < 4; r++) rowsum[mi][r] = 0.0f;
    for (int ni = 0; ni < 4; ni++) {
        int gcol = n0 + wcol + ni * 16 + ln;
        float bv = b2[gcol];
        for (int mi = 0; mi < 4; mi++)
            for (int r = 0; r < 4; r++)
                rowsum[mi][r] += __expf(acc[mi][ni][r] + bv);
    }
    // reduce across the 16 column-lanes (low 4 lane bits)
    for (int mi = 0; mi < 4; mi++)
        for (int r = 0; r < 4; r++) {
            float s = rowsum[mi][r];
            s += __shfl_xor(s, 1);
            s += __shfl_xor(s, 2);
            s += __shfl_xor(s, 4);
            s += __shfl_xor(s, 8);
            rowsum[mi][r] = s;
        }
    if (ln == 0) {
        for (int mi = 0; mi < 4; mi++)
            for (int r = 0; r < 4; r++) {
                int gm = m0 + wrow + mi * 16 + q * 4 + r;
                atomicAdd(&sumexp[(size_t)gm * 2 + branch], rowsum[mi][r]);
            }
    }
}

// ---------------------------------------------------------------------------
// Label logits: lab[m*2+branch] = dot(H[m,:], W2T[col,:]) + b2[col],
// col = branch*V + seq[b, (branch ? bi : fi)[n]].  One wave per (m, branch).
// ---------------------------------------------------------------------------
__global__ void label_logit_kernel(const __bf16* __restrict__ H,
                                   const __bf16* __restrict__ W2T,
                                   const float* __restrict__ b2,
                                   const int* __restrict__ seq,
                                   const int* __restrict__ fi,
                                   const int* __restrict__ bi,
                                   float* __restrict__ lab, int N, int M) {
    int wid  = (blockIdx.x * blockDim.x + threadIdx.x) >> 6;
    int lane = threadIdx.x & 63;
    if (wid >= M * 2) return;
    int m = wid >> 1, branch = wid & 1;
    int b = m / N, n = m - b * N;
    int tok = branch ? seq[b * L + bi[n]] : seq[b * L + fi[n]];
    int col = branch * V + tok;
    bf16x8 hv = *(const bf16x8*)(H   + (size_t)m   * K2 + lane * 8);
    bf16x8 wv = *(const bf16x8*)(W2T + (size_t)col * K2 + lane * 8);
    float s = 0.0f;
    for (int j = 0; j < 8; j++) s += (float)hv[j] * (float)wv[j];
    s += __shfl_xor(s, 32);
    s += __shfl_xor(s, 16);
    s += __shfl_xor(s, 8);
    s += __shfl_xor(s, 4);
    s += __shfl_xor(s, 2);
    s += __shfl_xor(s, 1);
    if (lane == 0) lab[wid] = s + b2[col];
}

// ---------------------------------------------------------------------------
// Final reduce: out = mean over (m, branch) of weight[branch] * nll where
// nll = log(sumexp) - label_logit, weights (1.0, 0.25).
// ---------------------------------------------------------------------------
__global__ void final_reduce_kernel(const float* __restrict__ sumexp,
                                    const float* __restrict__ lab,
                                    float* __restrict__ out, int M) {
    __shared__ float red[4];
    float acc = 0.0f;
    for (int m = threadIdx.x; m < M; m += 256) {
        float nf = logf(sumexp[m * 2 + 0]) - lab[m * 2 + 0];
        float nb = logf(sumexp[m * 2 + 1]) - lab[m * 2 + 1];
        acc += nf + 0.25f * nb;
    }
    acc += __shfl_xor(acc, 32);
    acc += __shfl_xor(acc, 16);
    acc += __shfl_xor(acc, 8);
    acc += __shfl_xor(acc, 4);
    acc += __shfl_xor(acc, 2);
    acc += __shfl_xor(acc, 1);
    int wv = threadIdx.x >> 6, ln = threadIdx.x & 63;
    if (ln == 0) red[wv] = acc;
    __syncthreads();
    if (threadIdx.x == 0)
        out[0] = (red[0] + red[1] + red[2] + red[3]) / (float)(2 * M);
}

// ---------------------------------------------------------------------------
extern "C" void kernel_launch(void* const* d_in, const int* in_sizes, int n_in,
                              void* d_out, int out_size, void* d_ws, size_t ws_size,
                              hipStream_t stream) {
    const float* fwd = (const float*)d_in[0];
    const float* bwd = (const float*)d_in[1];
    const int*   seq = (const int*)d_in[2];
    const int*   fi  = (const int*)d_in[3];
    const int*   bi  = (const int*)d_in[4];
    const float* w1  = (const float*)d_in[5];
    const float* b1  = (const float*)d_in[6];
    const float* w2  = (const float*)d_in[7];
    const float* b2  = (const float*)d_in[8];
    float* out = (float*)d_out;

    const int N    = in_sizes[3];          // 1303
    const int M    = Bsz * N;              // 2606
    const int Mpad = ((M + 127) / 128) * 128;  // 2688

    // workspace layout (16B-aligned slices)
    char* ws = (char*)d_ws;
    __bf16* A1  = (__bf16*)(ws);                                    // Mpad*1024
    __bf16* W1T = (__bf16*)(ws + (size_t)Mpad * K1 * 2);            // 512*1024
    __bf16* H   = (__bf16*)((char*)W1T + (size_t)N1 * K1 * 2);      // Mpad*512
    __bf16* W2T = (__bf16*)((char*)H   + (size_t)Mpad * N1 * 2);    // 64000*512
    float* sumexp = (float*)((char*)W2T + (size_t)N2 * K2 * 2);     // Mpad*2
    float* lab    = (float*)((char*)sumexp + (size_t)Mpad * 2 * 4); // M*2

    // 1. gather + cast
    {
        int total = Mpad * (K1 / 8);
        gather_cast_kernel<<<(total + 255) / 256, 256, 0, stream>>>(
            fwd, bwd, fi, bi, A1, N, M, Mpad);
    }
    // 2. transpose+cast weights
    transpose_cast_kernel<<<dim3(N1 / 64, K1 / 64), 256, 0, stream>>>(w1, W1T, K1, N1);
    transpose_cast_kernel<<<dim3(N2 / 64, K2 / 64), 256, 0, stream>>>(w2, W2T, K2, N2);
    // 3. zero sumexp accumulators
    hipMemsetAsync(sumexp, 0, (size_t)Mpad * 2 * sizeof(float), stream);
    // 4. GEMM1 -> H
    gemm1_kernel<<<dim3(N1 / 128, Mpad / 128), 256, 0, stream>>>(A1, W1T, b1, H, K1);
    // 5. GEMM2 fused exp-rowsum
    gemm2_kernel<<<dim3(N2 / 128, Mpad / 128), 256, 0, stream>>>(H, W2T, b2, sumexp, K2);
    // 6. label logits
    {
        int waves = M * 2;
        label_logit_kernel<<<(waves + 3) / 4, 256, 0, stream>>>(
            H, W2T, b2, seq, fi, bi, lab, N, M);
    }
    // 7. final scalar
    final_reduce_kernel<<<1, 256, 0, stream>>>(sumexp, lab, out, M);
}

// Round 2
// 910.371 us; speedup vs baseline: 1.0016x; 1.0016x over previous
//
#include <hip/hip_runtime.h>

// ---------------------------------------------------------------------------
// BeliefStateWrapper: gather(fi,bi) -> Linear(1024->512)+LeakyReLU ->
// Linear(512->64000) -> per-branch log_softmax NLL -> weighted mean (scalar).
//
// R2: GEMM2 restructured as persistent 64-column-strip blocks: W2 strip is
// staged fp32->bf16 into LDS ONCE per block (W2 fetched exactly once from
// HBM, 131 MB), then a barrier-free loop over all row tiles with A read
// directly from global (H = 2.9 MB, L2-resident). Label logits fused into
// the GEMM2 epilogue via labcol compare. Deletes W2 transpose + label kernel.
// ---------------------------------------------------------------------------

typedef __bf16 bf16x8 __attribute__((ext_vector_type(8)));
typedef __bf16 bf16x4 __attribute__((ext_vector_type(4)));
typedef float f32x4  __attribute__((ext_vector_type(4)));

#define MFMA16(a, b, c) __builtin_amdgcn_mfma_f32_16x16x32_bf16(a, b, c, 0, 0, 0)

static constexpr int Bsz   = 2;
static constexpr int L     = 512;
static constexpr int D     = 512;
static constexpr int V     = 32000;
static constexpr int K1    = 2 * D;      // 1024
static constexpr int N1    = D;          // 512
static constexpr int K2    = D;          // 512
static constexpr int N2    = 2 * V;      // 64000
static constexpr int BPAD  = 520;        // LDS row stride (16B-aligned, bank-spread)

// ---------------------------------------------------------------------------
// gather + cast to bf16.  A1[m][k], m = b*N + n, k in [0,1024):
//   k < 512 -> fwd[b, fi[n], k]; else bwd[b, bi[n], k-512].  Pad rows = 0.
// ---------------------------------------------------------------------------
__global__ void gather_cast_kernel(const float* __restrict__ fwd,
                                   const float* __restrict__ bwd,
                                   const int* __restrict__ fi,
                                   const int* __restrict__ bi,
                                   __bf16* __restrict__ A1,
                                   int N, int M, int Mpad) {
    int t = blockIdx.x * 256 + threadIdx.x;          // one thread = 8 elems
    int total = Mpad * (K1 / 8);
    if (t >= total) return;
    int m  = t >> 7;              // / (1024/8)
    int c8 = (t & 127) * 8;
    bf16x8 out;
    if (m < M) {
        int b = m / N;
        int n = m - b * N;
        const float* src;
        if (c8 < D) src = fwd + ((size_t)(b * L + fi[n])) * D + c8;
        else        src = bwd + ((size_t)(b * L + bi[n])) * D + (c8 - D);
        float4 v0 = *(const float4*)(src);
        float4 v1 = *(const float4*)(src + 4);
        out[0] = (__bf16)v0.x; out[1] = (__bf16)v0.y;
        out[2] = (__bf16)v0.z; out[3] = (__bf16)v0.w;
        out[4] = (__bf16)v1.x; out[5] = (__bf16)v1.y;
        out[6] = (__bf16)v1.z; out[7] = (__bf16)v1.w;
    } else {
        for (int j = 0; j < 8; j++) out[j] = (__bf16)0.0f;
    }
    *(bf16x8*)(A1 + (size_t)m * K1 + c8) = out;
}

// ---------------------------------------------------------------------------
// labcol[m*2+b] = b*V + seq[batch(m)*L + (b?bi:fi)[n]]  (or -1 for pad rows)
// ---------------------------------------------------------------------------
__global__ void labcol_kernel(const int* __restrict__ seq,
                              const int* __restrict__ fi,
                              const int* __restrict__ bi,
                              int* __restrict__ labcol, int N, int M, int Mpad) {
    int t = blockIdx.x * 256 + threadIdx.x;
    if (t >= Mpad * 2) return;
    int m = t >> 1, br = t & 1;
    if (m >= M) { labcol[t] = -1; return; }
    int b = m / N, n = m - b * N;
    int tok = br ? seq[b * L + bi[n]] : seq[b * L + fi[n]];
    labcol[t] = br * V + tok;
}

// ---------------------------------------------------------------------------
// transpose + cast fp32 [K][Nn] -> bf16 [Nn][K] (k-contiguous rows). w1 only.
// ---------------------------------------------------------------------------
__global__ void transpose_cast_kernel(const float* __restrict__ src,
                                      __bf16* __restrict__ dst,
                                      int K, int Nn) {
    __shared__ __align__(16) __bf16 tile[64][68];
    int t  = threadIdx.x;
    int tx = t & 15, ty = t >> 4;
    int n0 = blockIdx.x * 64, k0 = blockIdx.y * 64;
    for (int i = 0; i < 4; i++) {
        int k = k0 + ty + 16 * i;
        float4 v = *(const float4*)(src + (size_t)k * Nn + n0 + tx * 4);
        tile[tx * 4 + 0][ty + 16 * i] = (__bf16)v.x;
        tile[tx * 4 + 1][ty + 16 * i] = (__bf16)v.y;
        tile[tx * 4 + 2][ty + 16 * i] = (__bf16)v.z;
        tile[tx * 4 + 3][ty + 16 * i] = (__bf16)v.w;
    }
    __syncthreads();
    for (int i = 0; i < 4; i++) {
        int n = n0 + ty + 16 * i;
        bf16x4 o;
        o[0] = tile[ty + 16 * i][tx * 4 + 0];
        o[1] = tile[ty + 16 * i][tx * 4 + 1];
        o[2] = tile[ty + 16 * i][tx * 4 + 2];
        o[3] = tile[ty + 16 * i][tx * 4 + 3];
        *(bf16x4*)(dst + (size_t)n * K + k0 + tx * 4) = o;
    }
}

// ---------------------------------------------------------------------------
// GEMM1: H = leaky_relu(A1 @ W1 + b1), bf16 [Mpad][512].
// 128x128 tile, 4 waves (2x2), 16x16x32 MFMA, BK=32.
// ---------------------------------------------------------------------------
__global__ __launch_bounds__(256) void gemm1_kernel(
        const __bf16* __restrict__ A, const __bf16* __restrict__ Bt,
        const float* __restrict__ bias, __bf16* __restrict__ H, int K) {
    __shared__ __align__(16) __bf16 At[128][40];
    __shared__ __align__(16) __bf16 Bl[128][40];
    const int t = threadIdx.x;
    const int m0 = blockIdx.y * 128, n0 = blockIdx.x * 128;
    const int srow = t >> 2, schunk = (t & 3) * 8;
    const int wave = t >> 6, lane = t & 63;
    const int wrow = (wave >> 1) * 64, wcol = (wave & 1) * 64;
    const int q = lane >> 4, ln = lane & 15;

    f32x4 acc[4][4] = {};
    for (int k0 = 0; k0 < K; k0 += 32) {
        __syncthreads();
        *(bf16x8*)&At[srow][schunk]      = *(const bf16x8*)(A  + (size_t)(m0 + srow)      * K + k0 + schunk);
        *(bf16x8*)&At[srow + 64][schunk] = *(const bf16x8*)(A  + (size_t)(m0 + srow + 64) * K + k0 + schunk);
        *(bf16x8*)&Bl[srow][schunk]      = *(const bf16x8*)(Bt + (size_t)(n0 + srow)      * K + k0 + schunk);
        *(bf16x8*)&Bl[srow + 64][schunk] = *(const bf16x8*)(Bt + (size_t)(n0 + srow + 64) * K + k0 + schunk);
        __syncthreads();
        bf16x8 af[4], bfr[4];
        for (int i = 0; i < 4; i++) af[i]  = *(const bf16x8*)&At[wrow + i * 16 + ln][q * 8];
        for (int i = 0; i < 4; i++) bfr[i] = *(const bf16x8*)&Bl[wcol + i * 16 + ln][q * 8];
        for (int mi = 0; mi < 4; mi++)
            for (int ni = 0; ni < 4; ni++)
                acc[mi][ni] = MFMA16(af[mi], bfr[ni], acc[mi][ni]);
    }
    for (int ni = 0; ni < 4; ni++) {
        int gcol = n0 + wcol + ni * 16 + ln;
        float bv = bias[gcol];
        for (int mi = 0; mi < 4; mi++)
            for (int r = 0; r < 4; r++) {
                int gm = m0 + wrow + mi * 16 + q * 4 + r;
                float v = acc[mi][ni][r] + bv;
                v = v > 0.0f ? v : 0.01f * v;
                H[(size_t)gm * N1 + gcol] = (__bf16)v;
            }
    }
}

// ---------------------------------------------------------------------------
// GEMM2 (persistent column strip): block owns cols [c0, c0+64). Stage
// W2[:, strip] fp32->bf16 into LDS once, then loop all row tiles (256 rows,
// 4 waves x 64 rows) with NO barriers: A frags direct from global (L2-hot).
// Epilogue per tile: exp-rowsum -> shuffle reduce -> atomicAdd sumexp;
// label logit extracted when gcol == labcol[m][branch].
// ---------------------------------------------------------------------------
__global__ __launch_bounds__(256, 2) void gemm2_kernel(
        const __bf16* __restrict__ A, const float* __restrict__ w2,
        const float* __restrict__ b2, const int* __restrict__ labcol,
        float* __restrict__ sumexp, float* __restrict__ lab, int Mpad) {
    __shared__ __align__(16) __bf16 Bl[64][BPAD];
    const int t = threadIdx.x;
    const int c0 = blockIdx.x * 64;
    const int branch = (c0 >= V) ? 1 : 0;

    // ---- stage W2 strip: fp32 [512][64000] -> bf16 LDS [64 cols][512 k]
    {
        const int col = t & 63;
        const int kb0 = (t >> 6) * 8;
        for (int r = 0; r < 16; r++) {
            int kb = kb0 + r * 32;
            float v[8];
#pragma unroll
            for (int j = 0; j < 8; j++)
                v[j] = w2[(size_t)(kb + j) * N2 + c0 + col];
            bf16x8 o;
#pragma unroll
            for (int j = 0; j < 8; j++) o[j] = (__bf16)v[j];
            *(bf16x8*)&Bl[col][kb] = o;
        }
    }
    __syncthreads();

    const int wave = t >> 6, lane = t & 63;
    const int wrow = wave * 64;
    const int q = lane >> 4, ln = lane & 15;

    // B frags are row-tile invariant: load once. bfr[ni][k-step]
    bf16x8 bfr[4][16];
#pragma unroll
    for (int ni = 0; ni < 4; ni++)
#pragma unroll
        for (int ks = 0; ks < 16; ks++)
            bfr[ni][ks] = *(const bf16x8*)&Bl[ni * 16 + ln][ks * 32 + q * 8];
    // hold only the first 4 k-steps in registers? No: 4*16*4 VGPRs = 256 too
    // many -- compiler would spill. Re-read from LDS per tile instead.
    // (The loop above is intentionally NOT kept live; see tile loop below.)

    float bvn[4];
#pragma unroll
    for (int ni = 0; ni < 4; ni++) bvn[ni] = b2[c0 + ni * 16 + ln];

    const int RT = Mpad >> 8;   // 256-row tiles
    for (int rt = 0; rt < RT; rt++) {
        const int m0 = rt * 256;
        const __bf16* Ab = A + (size_t)(m0 + wrow + ln) * K2 + q * 8;

        f32x4 acc[4][4] = {};
#pragma unroll 4
        for (int ks = 0; ks < 16; ks++) {
            const int k0 = ks * 32;
            bf16x8 af[4], bf[4];
#pragma unroll
            for (int mi = 0; mi < 4; mi++)
                af[mi] = *(const bf16x8*)(Ab + (size_t)mi * 16 * K2 + k0);
#pragma unroll
            for (int ni = 0; ni < 4; ni++)
                bf[ni] = *(const bf16x8*)&Bl[ni * 16 + ln][k0 + q * 8];
#pragma unroll
            for (int mi = 0; mi < 4; mi++)
#pragma unroll
                for (int ni = 0; ni < 4; ni++)
                    acc[mi][ni] = MFMA16(af[mi], bf[ni], acc[mi][ni]);
        }

        // ---- epilogue for this tile
        int lc[4][4];
#pragma unroll
        for (int mi = 0; mi < 4; mi++)
#pragma unroll
            for (int r = 0; r < 4; r++)
                lc[mi][r] = labcol[(m0 + wrow + mi * 16 + q * 4 + r) * 2 + branch];

        float rowsum[4][4];
#pragma unroll
        for (int mi = 0; mi < 4; mi++)
#pragma unroll
            for (int r = 0; r < 4; r++) rowsum[mi][r] = 0.0f;

#pragma unroll
        for (int ni = 0; ni < 4; ni++) {
            const int gcol = c0 + ni * 16 + ln;
            const float bv = bvn[ni];
#pragma unroll
            for (int mi = 0; mi < 4; mi++)
#pragma unroll
                for (int r = 0; r < 4; r++) {
                    float v = acc[mi][ni][r] + bv;
                    rowsum[mi][r] += __expf(v);
                    if (gcol == lc[mi][r]) {
                        int gm = m0 + wrow + mi * 16 + q * 4 + r;
                        lab[gm * 2 + branch] = v;
                    }
                }
        }
#pragma unroll
        for (int mi = 0; mi < 4; mi++)
#pragma unroll
            for (int r = 0; r < 4; r++) {
                float s = rowsum[mi][r];
                s += __shfl_xor(s, 1);
                s += __shfl_xor(s, 2);
                s += __shfl_xor(s, 4);
                s += __shfl_xor(s, 8);
                if (ln == 0) {
                    int gm = m0 + wrow + mi * 16 + q * 4 + r;
                    atomicAdd(&sumexp[gm * 2 + branch], s);
                }
            }
    }
}

// ---------------------------------------------------------------------------
// Final reduce: out = mean over (m, branch) of weight[branch] * nll,
// nll = log(sumexp) - label_logit, weights (1.0, 0.25).
// ---------------------------------------------------------------------------
__global__ void final_reduce_kernel(const float* __restrict__ sumexp,
                                    const float* __restrict__ lab,
                                    float* __restrict__ out, int M) {
    __shared__ float red[4];
    float acc = 0.0f;
    for (int m = threadIdx.x; m < M; m += 256) {
        float nf = logf(sumexp[m * 2 + 0]) - lab[m * 2 + 0];
        float nb = logf(sumexp[m * 2 + 1]) - lab[m * 2 + 1];
        acc += nf + 0.25f * nb;
    }
    acc += __shfl_xor(acc, 32);
    acc += __shfl_xor(acc, 16);
    acc += __shfl_xor(acc, 8);
    acc += __shfl_xor(acc, 4);
    acc += __shfl_xor(acc, 2);
    acc += __shfl_xor(acc, 1);
    int wv = threadIdx.x >> 6, ln = threadIdx.x & 63;
    if (ln == 0) red[wv] = acc;
    __syncthreads();
    if (threadIdx.x == 0)
        out[0] = (red[0] + red[1] + red[2] + red[3]) / (float)(2 * M);
}

// ---------------------------------------------------------------------------
extern "C" void kernel_launch(void* const* d_in, const int* in_sizes, int n_in,
                              void* d_out, int out_size, void* d_ws, size_t ws_size,
                              hipStream_t stream) {
    const float* fwd = (const float*)d_in[0];
    const float* bwd = (const float*)d_in[1];
    const int*   seq = (const int*)d_in[2];
    const int*   fi  = (const int*)d_in[3];
    const int*   bi  = (const int*)d_in[4];
    const float* w1  = (const float*)d_in[5];
    const float* b1  = (const float*)d_in[6];
    const float* w2  = (const float*)d_in[7];
    const float* b2  = (const float*)d_in[8];
    float* out = (float*)d_out;

    const int N    = in_sizes[3];              // 1303
    const int M    = Bsz * N;                  // 2606
    const int Mpad = ((M + 255) / 256) * 256;  // 2816

    // workspace layout (16B-aligned slices)
    char* ws = (char*)d_ws;
    __bf16* A1  = (__bf16*)(ws);                                    // Mpad*1024
    __bf16* W1T = (__bf16*)(ws + (size_t)Mpad * K1 * 2);            // 512*1024
    __bf16* H   = (__bf16*)((char*)W1T + (size_t)N1 * K1 * 2);      // Mpad*512
    float*  sumexp = (float*)((char*)H + (size_t)Mpad * N1 * 2);    // Mpad*2
    float*  lab    = (float*)((char*)sumexp + (size_t)Mpad * 2 * 4);// Mpad*2
    int*    labcol = (int*)((char*)lab + (size_t)Mpad * 2 * 4);     // Mpad*2

    // 1. gather + cast (zero-fills pad rows)
    {
        int total = Mpad * (K1 / 8);
        gather_cast_kernel<<<(total + 255) / 256, 256, 0, stream>>>(
            fwd, bwd, fi, bi, A1, N, M, Mpad);
    }
    // 2. label columns
    labcol_kernel<<<(Mpad * 2 + 255) / 256, 256, 0, stream>>>(
        seq, fi, bi, labcol, N, M, Mpad);
    // 3. transpose+cast w1 only
    transpose_cast_kernel<<<dim3(N1 / 64, K1 / 64), 256, 0, stream>>>(w1, W1T, K1, N1);
    // 4. zero sumexp accumulators
    hipMemsetAsync(sumexp, 0, (size_t)Mpad * 2 * sizeof(float), stream);
    // 5. GEMM1 -> H
    gemm1_kernel<<<dim3(N1 / 128, Mpad / 128), 256, 0, stream>>>(A1, W1T, b1, H, K1);
    // 6. GEMM2 persistent strips, fused exp-rowsum + label extraction
    gemm2_kernel<<<N2 / 64, 256, 0, stream>>>(H, w2, b2, labcol, sumexp, lab, Mpad);
    // 7. final scalar
    final_reduce_kernel<<<1, 256, 0, stream>>>(sumexp, lab, out, M);
}

// Round 3
// 465.600 us; speedup vs baseline: 1.9584x; 1.9553x over previous
//
#include <hip/hip_runtime.h>

// ---------------------------------------------------------------------------
// BeliefStateWrapper: gather(fi,bi) -> Linear(1024->512)+LeakyReLU ->
// Linear(512->64000) -> per-branch log_softmax NLL -> weighted mean (scalar).
//
// R3: GEMM2 A-path fixed. GEMM1 emits H in MFMA-fragment-major "Apack"
// layout (1 KB chunk per (panel,ks,mi), lane-contiguous), so GEMM2 reads A
// as perfectly-coalesced 16 B/lane streams from L2 (no LDS for A, no
// barriers in the hot loop). W2 staged with NON-TEMPORAL loads so the
// 131 MB stream does not evict Apack (2.9 MB) from L2. sumexp atomics
// replaced by per-strip partial sums + reduce kernel.
// ---------------------------------------------------------------------------

typedef __bf16 bf16x8 __attribute__((ext_vector_type(8)));
typedef __bf16 bf16x4 __attribute__((ext_vector_type(4)));
typedef float f32x4  __attribute__((ext_vector_type(4)));

#define MFMA16(a, b, c) __builtin_amdgcn_mfma_f32_16x16x32_bf16(a, b, c, 0, 0, 0)

static constexpr int Bsz   = 2;
static constexpr int L     = 512;
static constexpr int D     = 512;
static constexpr int V     = 32000;
static constexpr int K1    = 2 * D;      // 1024
static constexpr int N1    = D;          // 512
static constexpr int K2    = D;          // 512
static constexpr int N2    = 2 * V;      // 64000
static constexpr int BPAD  = 520;        // LDS row stride for W2 strip
static constexpr int NSTRIP = N2 / 64;   // 1000 strips (500 per branch)

// Apack chunk base (in bf16 elements) for (panel, ks, mi); chunk = 64 lanes
// x 8 bf16 = 512 elems = 1 KB. Lane l holds A[panel*64+mi*16+(l&15)]
// [ks*32+(l>>4)*8 .. +7].
__device__ __host__ inline size_t apack_chunk(int panel, int ks, int mi) {
    return (((size_t)panel * 16 + ks) * 4 + mi) * 512;
}

// ---------------------------------------------------------------------------
// gather + cast to bf16.  A1[m][k], m = b*N + n, k in [0,1024):
//   k < 512 -> fwd[b, fi[n], k]; else bwd[b, bi[n], k-512].  Pad rows = 0.
// ---------------------------------------------------------------------------
__global__ void gather_cast_kernel(const float* __restrict__ fwd,
                                   const float* __restrict__ bwd,
                                   const int* __restrict__ fi,
                                   const int* __restrict__ bi,
                                   __bf16* __restrict__ A1,
                                   int N, int M, int Mpad) {
    int t = blockIdx.x * 256 + threadIdx.x;          // one thread = 8 elems
    int total = Mpad * (K1 / 8);
    if (t >= total) return;
    int m  = t >> 7;              // / (1024/8)
    int c8 = (t & 127) * 8;
    bf16x8 out;
    if (m < M) {
        int b = m / N;
        int n = m - b * N;
        const float* src;
        if (c8 < D) src = fwd + ((size_t)(b * L + fi[n])) * D + c8;
        else        src = bwd + ((size_t)(b * L + bi[n])) * D + (c8 - D);
        float4 v0 = *(const float4*)(src);
        float4 v1 = *(const float4*)(src + 4);
        out[0] = (__bf16)v0.x; out[1] = (__bf16)v0.y;
        out[2] = (__bf16)v0.z; out[3] = (__bf16)v0.w;
        out[4] = (__bf16)v1.x; out[5] = (__bf16)v1.y;
        out[6] = (__bf16)v1.z; out[7] = (__bf16)v1.w;
    } else {
        for (int j = 0; j < 8; j++) out[j] = (__bf16)0.0f;
    }
    *(bf16x8*)(A1 + (size_t)m * K1 + c8) = out;
}

// ---------------------------------------------------------------------------
// labcol[m*2+b] = b*V + seq[batch(m)*L + (b?bi:fi)[n]]  (or -1 for pad rows)
// ---------------------------------------------------------------------------
__global__ void labcol_kernel(const int* __restrict__ seq,
                              const int* __restrict__ fi,
                              const int* __restrict__ bi,
                              int* __restrict__ labcol, int N, int M, int Mpad) {
    int t = blockIdx.x * 256 + threadIdx.x;
    if (t >= Mpad * 2) return;
    int m = t >> 1, br = t & 1;
    if (m >= M) { labcol[t] = -1; return; }
    int b = m / N, n = m - b * N;
    int tok = br ? seq[b * L + bi[n]] : seq[b * L + fi[n]];
    labcol[t] = br * V + tok;
}

// ---------------------------------------------------------------------------
// transpose + cast fp32 [K][Nn] -> bf16 [Nn][K] (k-contiguous rows). w1 only.
// ---------------------------------------------------------------------------
__global__ void transpose_cast_kernel(const float* __restrict__ src,
                                      __bf16* __restrict__ dst,
                                      int K, int Nn) {
    __shared__ __align__(16) __bf16 tile[64][68];
    int t  = threadIdx.x;
    int tx = t & 15, ty = t >> 4;
    int n0 = blockIdx.x * 64, k0 = blockIdx.y * 64;
    for (int i = 0; i < 4; i++) {
        int k = k0 + ty + 16 * i;
        float4 v = *(const float4*)(src + (size_t)k * Nn + n0 + tx * 4);
        tile[tx * 4 + 0][ty + 16 * i] = (__bf16)v.x;
        tile[tx * 4 + 1][ty + 16 * i] = (__bf16)v.y;
        tile[tx * 4 + 2][ty + 16 * i] = (__bf16)v.z;
        tile[tx * 4 + 3][ty + 16 * i] = (__bf16)v.w;
    }
    __syncthreads();
    for (int i = 0; i < 4; i++) {
        int n = n0 + ty + 16 * i;
        bf16x4 o;
        o[0] = tile[ty + 16 * i][tx * 4 + 0];
        o[1] = tile[ty + 16 * i][tx * 4 + 1];
        o[2] = tile[ty + 16 * i][tx * 4 + 2];
        o[3] = tile[ty + 16 * i][tx * 4 + 3];
        *(bf16x4*)(dst + (size_t)n * K + k0 + tx * 4) = o;
    }
}

// ---------------------------------------------------------------------------
// GEMM1: H = leaky_relu(A1 @ W1 + b1), emitted in Apack fragment-major
// layout.  128x128 tile, 4 waves (2x2), 16x16x32 MFMA, BK=32.  Epilogue
// round-trips C through LDS so the Apack stores are fully coalesced.
// ---------------------------------------------------------------------------
__global__ __launch_bounds__(256) void gemm1_kernel(
        const __bf16* __restrict__ A, const __bf16* __restrict__ Bt,
        const float* __restrict__ bias, __bf16* __restrict__ Apack, int K) {
    __shared__ __align__(16) __bf16 At[128][40];
    __shared__ __align__(16) __bf16 Bl[128][40];
    __shared__ __align__(16) __bf16 Cld[128][136];
    const int t = threadIdx.x;
    const int by = blockIdx.y, bx = blockIdx.x;
    const int m0 = by * 128, n0 = bx * 128;
    const int srow = t >> 2, schunk = (t & 3) * 8;
    const int wave = t >> 6, lane = t & 63;
    const int wrow = (wave >> 1) * 64, wcol = (wave & 1) * 64;
    const int q = lane >> 4, ln = lane & 15;

    f32x4 acc[4][4] = {};
    for (int k0 = 0; k0 < K; k0 += 32) {
        __syncthreads();
        *(bf16x8*)&At[srow][schunk]      = *(const bf16x8*)(A  + (size_t)(m0 + srow)      * K + k0 + schunk);
        *(bf16x8*)&At[srow + 64][schunk] = *(const bf16x8*)(A  + (size_t)(m0 + srow + 64) * K + k0 + schunk);
        *(bf16x8*)&Bl[srow][schunk]      = *(const bf16x8*)(Bt + (size_t)(n0 + srow)      * K + k0 + schunk);
        *(bf16x8*)&Bl[srow + 64][schunk] = *(const bf16x8*)(Bt + (size_t)(n0 + srow + 64) * K + k0 + schunk);
        __syncthreads();
        bf16x8 af[4], bfr[4];
        for (int i = 0; i < 4; i++) af[i]  = *(const bf16x8*)&At[wrow + i * 16 + ln][q * 8];
        for (int i = 0; i < 4; i++) bfr[i] = *(const bf16x8*)&Bl[wcol + i * 16 + ln][q * 8];
        for (int mi = 0; mi < 4; mi++)
            for (int ni = 0; ni < 4; ni++)
                acc[mi][ni] = MFMA16(af[mi], bfr[ni], acc[mi][ni]);
    }
    // bias + leaky -> LDS C tile
    for (int ni = 0; ni < 4; ni++) {
        int gcol = n0 + wcol + ni * 16 + ln;
        float bv = bias[gcol];
        for (int mi = 0; mi < 4; mi++)
            for (int r = 0; r < 4; r++) {
                float v = acc[mi][ni][r] + bv;
                v = v > 0.0f ? v : 0.01f * v;
                Cld[wrow + mi * 16 + q * 4 + r][wcol + ni * 16 + ln] = (__bf16)v;
            }
    }
    __syncthreads();
    // pack out: 32 chunks (pl 0..1, ksl 0..3, mi 0..3), wave w -> c = w+4i
    for (int i = 0; i < 8; i++) {
        int c   = wave + 4 * i;
        int pl  = c >> 4, ksl = (c >> 2) & 3, mi = c & 3;
        int row = pl * 64 + mi * 16 + (lane & 15);
        int col = ksl * 32 + (lane >> 4) * 8;
        bf16x8 v = *(const bf16x8*)&Cld[row][col];
        size_t base = apack_chunk(2 * by + pl, 4 * bx + ksl, mi);
        *(bf16x8*)(Apack + base + lane * 8) = v;
    }
}

// ---------------------------------------------------------------------------
// GEMM2 (persistent 64-col strip): stage W2 strip fp32->bf16 into LDS once
// (NON-TEMPORAL so the stream doesn't evict Apack from L2), then each wave
// sweeps panels of 64 rows reading Apack as coalesced 16 B/lane streams with
// one-k-step prefetch.  Epilogue: exp-rowsum -> shuffle reduce -> per-lane
// row gather -> coalesced partial store; label logit via labcol compare.
// ---------------------------------------------------------------------------
__global__ __launch_bounds__(256, 2) void gemm2_kernel(
        const __bf16* __restrict__ Apack, const float* __restrict__ w2,
        const float* __restrict__ b2, const int* __restrict__ labcol,
        float* __restrict__ partial, float* __restrict__ lab, int Mpad) {
    __shared__ __align__(16) __bf16 Bl[64][BPAD];
    const int t = threadIdx.x;
    const int strip = blockIdx.x;
    const int c0 = strip * 64;
    const int branch = (c0 >= V) ? 1 : 0;

    // ---- stage W2 strip: fp32 [512][64000] -> bf16 LDS [64 cols][512 k]
    {
        const int col = t & 63;
        const int kb0 = (t >> 6) * 8;
        for (int r = 0; r < 16; r++) {
            int kb = kb0 + r * 32;
            float v[8];
#pragma unroll
            for (int j = 0; j < 8; j++)
                v[j] = __builtin_nontemporal_load(w2 + (size_t)(kb + j) * N2 + c0 + col);
            bf16x8 o;
#pragma unroll
            for (int j = 0; j < 8; j++) o[j] = (__bf16)v[j];
            *(bf16x8*)&Bl[col][kb] = o;
        }
    }
    __syncthreads();

    const int wave = t >> 6, lane = t & 63;
    const int q = lane >> 4, ln = lane & 15;

    float bvn[4];
#pragma unroll
    for (int ni = 0; ni < 4; ni++) bvn[ni] = b2[c0 + ni * 16 + ln];

    const int npanels = Mpad >> 6;
    for (int p = wave; p < npanels; p += 4) {
        const __bf16* base = Apack + apack_chunk(p, 0, 0) + lane * 8;

        f32x4 acc[4][4] = {};
        bf16x8 afc[4], afn[4];
#pragma unroll
        for (int mi = 0; mi < 4; mi++)
            afc[mi] = *(const bf16x8*)(base + mi * 512);
#pragma unroll 1
        for (int ks = 0; ks < 16; ks++) {
            if (ks < 15) {
#pragma unroll
                for (int mi = 0; mi < 4; mi++)
                    afn[mi] = *(const bf16x8*)(base + (size_t)(ks + 1) * 2048 + mi * 512);
            }
            bf16x8 bf[4];
#pragma unroll
            for (int ni = 0; ni < 4; ni++)
                bf[ni] = *(const bf16x8*)&Bl[ni * 16 + ln][ks * 32 + q * 8];
#pragma unroll
            for (int mi = 0; mi < 4; mi++)
#pragma unroll
                for (int ni = 0; ni < 4; ni++)
                    acc[mi][ni] = MFMA16(afc[mi], bf[ni], acc[mi][ni]);
#pragma unroll
            for (int mi = 0; mi < 4; mi++) afc[mi] = afn[mi];
        }

        // ---- epilogue for this panel
        int lc[4][4];
#pragma unroll
        for (int mi = 0; mi < 4; mi++)
#pragma unroll
            for (int r = 0; r < 4; r++)
                lc[mi][r] = labcol[(p * 64 + mi * 16 + q * 4 + r) * 2 + branch];

        float rowsum[4][4];
#pragma unroll
        for (int mi = 0; mi < 4; mi++)
#pragma unroll
            for (int r = 0; r < 4; r++) rowsum[mi][r] = 0.0f;

#pragma unroll
        for (int ni = 0; ni < 4; ni++) {
            const int gcol = c0 + ni * 16 + ln;
            const float bv = bvn[ni];
#pragma unroll
            for (int mi = 0; mi < 4; mi++)
#pragma unroll
                for (int r = 0; r < 4; r++) {
                    float v = acc[mi][ni][r] + bv;
                    rowsum[mi][r] += __expf(v);
                    if (gcol == lc[mi][r]) {
                        int gm = p * 64 + mi * 16 + q * 4 + r;
                        lab[gm * 2 + branch] = v;
                    }
                }
        }
        // reduce over the 16 column-lanes (lane bits 0..3)
#pragma unroll
        for (int mi = 0; mi < 4; mi++)
#pragma unroll
            for (int r = 0; r < 4; r++) {
                float s = rowsum[mi][r];
                s += __shfl_xor(s, 1);
                s += __shfl_xor(s, 2);
                s += __shfl_xor(s, 4);
                s += __shfl_xor(s, 8);
                rowsum[mi][r] = s;
            }
        // per-lane row gather: lane l wants row l = mi*16 + q*4 + r, value
        // lives in lanes with q == (l>>2)&3 at register rowsum[l>>4][l&3].
        float mine = 0.0f;
        const int srcl = ((lane >> 2) & 3) * 16;
#pragma unroll
        for (int mi2 = 0; mi2 < 4; mi2++)
#pragma unroll
            for (int r2 = 0; r2 < 4; r2++) {
                float tv = __shfl(rowsum[mi2][r2], srcl);
                if ((lane >> 4) == mi2 && (lane & 3) == r2) mine = tv;
            }
        partial[(size_t)strip * Mpad + p * 64 + lane] = mine;
    }
}

// ---------------------------------------------------------------------------
// Reduce partials: sumexp[m*2+br] = sum over the branch's 500 strips.
// ---------------------------------------------------------------------------
__global__ void reduce_sumexp_kernel(const float* __restrict__ partial,
                                     float* __restrict__ sumexp, int Mpad) {
    int t = blockIdx.x * 256 + threadIdx.x;
    if (t >= Mpad * 2) return;
    int br = t / Mpad, m = t - br * Mpad;
    int s0 = br * (NSTRIP / 2), s1 = s0 + NSTRIP / 2;
    float s = 0.0f;
#pragma unroll 4
    for (int si = s0; si < s1; si++)
        s += partial[(size_t)si * Mpad + m];
    sumexp[m * 2 + br] = s;
}

// ---------------------------------------------------------------------------
// Final reduce: out = mean over (m, branch) of weight[branch] * nll,
// nll = log(sumexp) - label_logit, weights (1.0, 0.25).
// ---------------------------------------------------------------------------
__global__ void final_reduce_kernel(const float* __restrict__ sumexp,
                                    const float* __restrict__ lab,
                                    float* __restrict__ out, int M) {
    __shared__ float red[4];
    float acc = 0.0f;
    for (int m = threadIdx.x; m < M; m += 256) {
        float nf = logf(sumexp[m * 2 + 0]) - lab[m * 2 + 0];
        float nb = logf(sumexp[m * 2 + 1]) - lab[m * 2 + 1];
        acc += nf + 0.25f * nb;
    }
    acc += __shfl_xor(acc, 32);
    acc += __shfl_xor(acc, 16);
    acc += __shfl_xor(acc, 8);
    acc += __shfl_xor(acc, 4);
    acc += __shfl_xor(acc, 2);
    acc += __shfl_xor(acc, 1);
    int wv = threadIdx.x >> 6, ln = threadIdx.x & 63;
    if (ln == 0) red[wv] = acc;
    __syncthreads();
    if (threadIdx.x == 0)
        out[0] = (red[0] + red[1] + red[2] + red[3]) / (float)(2 * M);
}

// ---------------------------------------------------------------------------
extern "C" void kernel_launch(void* const* d_in, const int* in_sizes, int n_in,
                              void* d_out, int out_size, void* d_ws, size_t ws_size,
                              hipStream_t stream) {
    const float* fwd = (const float*)d_in[0];
    const float* bwd = (const float*)d_in[1];
    const int*   seq = (const int*)d_in[2];
    const int*   fi  = (const int*)d_in[3];
    const int*   bi  = (const int*)d_in[4];
    const float* w1  = (const float*)d_in[5];
    const float* b1  = (const float*)d_in[6];
    const float* w2  = (const float*)d_in[7];
    const float* b2  = (const float*)d_in[8];
    float* out = (float*)d_out;

    const int N    = in_sizes[3];              // 1303
    const int M    = Bsz * N;                  // 2606
    const int Mpad = ((M + 255) / 256) * 256;  // 2816

    // workspace layout (16B-aligned slices)
    char* ws = (char*)d_ws;
    __bf16* A1    = (__bf16*)(ws);                                   // Mpad*1024
    __bf16* W1T   = (__bf16*)(ws + (size_t)Mpad * K1 * 2);           // 512*1024
    __bf16* Apack = (__bf16*)((char*)W1T + (size_t)N1 * K1 * 2);     // Mpad*512
    float*  partial = (float*)((char*)Apack + (size_t)Mpad * N1 * 2);// NSTRIP*Mpad
    float*  sumexp  = (float*)((char*)partial + (size_t)NSTRIP * Mpad * 4); // Mpad*2
    float*  lab     = (float*)((char*)sumexp + (size_t)Mpad * 2 * 4);// Mpad*2
    int*    labcol  = (int*)((char*)lab + (size_t)Mpad * 2 * 4);     // Mpad*2

    // 1. gather + cast (zero-fills pad rows)
    {
        int total = Mpad * (K1 / 8);
        gather_cast_kernel<<<(total + 255) / 256, 256, 0, stream>>>(
            fwd, bwd, fi, bi, A1, N, M, Mpad);
    }
    // 2. label columns
    labcol_kernel<<<(Mpad * 2 + 255) / 256, 256, 0, stream>>>(
        seq, fi, bi, labcol, N, M, Mpad);
    // 3. transpose+cast w1
    transpose_cast_kernel<<<dim3(N1 / 64, K1 / 64), 256, 0, stream>>>(w1, W1T, K1, N1);
    // 4. GEMM1 -> Apack (fragment-major H)
    gemm1_kernel<<<dim3(N1 / 128, Mpad / 128), 256, 0, stream>>>(A1, W1T, b1, Apack, K1);
    // 5. GEMM2 persistent strips -> per-strip partial rowsums + labels
    gemm2_kernel<<<NSTRIP, 256, 0, stream>>>(Apack, w2, b2, labcol, partial, lab, Mpad);
    // 6. reduce partials -> sumexp
    reduce_sumexp_kernel<<<(Mpad * 2 + 255) / 256, 256, 0, stream>>>(partial, sumexp, Mpad);
    // 7. final scalar
    final_reduce_kernel<<<1, 256, 0, stream>>>(sumexp, lab, out, M);
}

// Round 4
// 441.766 us; speedup vs baseline: 2.0641x; 1.0540x over previous
//
#include <hip/hip_runtime.h>

// ---------------------------------------------------------------------------
// BeliefStateWrapper: gather(fi,bi) -> Linear(1024->512)+LeakyReLU ->
// Linear(512->64000) -> per-branch log_softmax NLL -> weighted mean (scalar).
//
// R4: gemm2 LDS B-strip stored fragment-major ("Bpack": 1 KB chunk per
// (ks,ni), lane-contiguous 16B lines -> conflict-free ds_read_b128), and
// blocks widened to 512 threads (8 waves, 2 blocks/CU = 16 waves/CU) for
// latency hiding. labcol folded into gather kernel.
// ---------------------------------------------------------------------------

typedef __bf16 bf16x8 __attribute__((ext_vector_type(8)));
typedef __bf16 bf16x4 __attribute__((ext_vector_type(4)));
typedef float f32x4  __attribute__((ext_vector_type(4)));

#define MFMA16(a, b, c) __builtin_amdgcn_mfma_f32_16x16x32_bf16(a, b, c, 0, 0, 0)

static constexpr int Bsz   = 2;
static constexpr int L     = 512;
static constexpr int D     = 512;
static constexpr int V     = 32000;
static constexpr int K1    = 2 * D;      // 1024
static constexpr int N1    = D;          // 512
static constexpr int K2    = D;          // 512
static constexpr int N2    = 2 * V;      // 64000
static constexpr int NSTRIP = N2 / 64;   // 1000 strips (500 per branch)

// Apack chunk base (bf16 elems) for (panel, ks, mi); chunk = 64 lanes x 8
// bf16 = 512 elems = 1 KB. Lane l holds A[panel*64+mi*16+(l&15)]
// [ks*32+(l>>4)*8 .. +7].
__device__ __host__ inline size_t apack_chunk(int panel, int ks, int mi) {
    return (((size_t)panel * 16 + ks) * 4 + mi) * 512;
}

// ---------------------------------------------------------------------------
// gather + cast to bf16 (+ labcol side-task).  A1[m][k], m = b*N + n:
//   k < 512 -> fwd[b, fi[n], k]; else bwd[b, bi[n], k-512].  Pad rows = 0.
// ---------------------------------------------------------------------------
__global__ void gather_cast_kernel(const float* __restrict__ fwd,
                                   const float* __restrict__ bwd,
                                   const int* __restrict__ fi,
                                   const int* __restrict__ bi,
                                   const int* __restrict__ seq,
                                   __bf16* __restrict__ A1,
                                   int* __restrict__ labcol,
                                   int N, int M, int Mpad) {
    int t = blockIdx.x * 256 + threadIdx.x;          // one thread = 8 elems
    // side-task: label columns (Mpad*2 entries)
    if (t < Mpad * 2) {
        int m = t >> 1, br = t & 1;
        if (m >= M) labcol[t] = -1;
        else {
            int b = m / N, n = m - b * N;
            int tok = br ? seq[b * L + bi[n]] : seq[b * L + fi[n]];
            labcol[t] = br * V + tok;
        }
    }
    int total = Mpad * (K1 / 8);
    if (t >= total) return;
    int m  = t >> 7;              // / (1024/8)
    int c8 = (t & 127) * 8;
    bf16x8 out;
    if (m < M) {
        int b = m / N;
        int n = m - b * N;
        const float* src;
        if (c8 < D) src = fwd + ((size_t)(b * L + fi[n])) * D + c8;
        else        src = bwd + ((size_t)(b * L + bi[n])) * D + (c8 - D);
        float4 v0 = *(const float4*)(src);
        float4 v1 = *(const float4*)(src + 4);
        out[0] = (__bf16)v0.x; out[1] = (__bf16)v0.y;
        out[2] = (__bf16)v0.z; out[3] = (__bf16)v0.w;
        out[4] = (__bf16)v1.x; out[5] = (__bf16)v1.y;
        out[6] = (__bf16)v1.z; out[7] = (__bf16)v1.w;
    } else {
        for (int j = 0; j < 8; j++) out[j] = (__bf16)0.0f;
    }
    *(bf16x8*)(A1 + (size_t)m * K1 + c8) = out;
}

// ---------------------------------------------------------------------------
// transpose + cast fp32 [K][Nn] -> bf16 [Nn][K] (k-contiguous rows). w1 only.
// ---------------------------------------------------------------------------
__global__ void transpose_cast_kernel(const float* __restrict__ src,
                                      __bf16* __restrict__ dst,
                                      int K, int Nn) {
    __shared__ __align__(16) __bf16 tile[64][68];
    int t  = threadIdx.x;
    int tx = t & 15, ty = t >> 4;
    int n0 = blockIdx.x * 64, k0 = blockIdx.y * 64;
    for (int i = 0; i < 4; i++) {
        int k = k0 + ty + 16 * i;
        float4 v = *(const float4*)(src + (size_t)k * Nn + n0 + tx * 4);
        tile[tx * 4 + 0][ty + 16 * i] = (__bf16)v.x;
        tile[tx * 4 + 1][ty + 16 * i] = (__bf16)v.y;
        tile[tx * 4 + 2][ty + 16 * i] = (__bf16)v.z;
        tile[tx * 4 + 3][ty + 16 * i] = (__bf16)v.w;
    }
    __syncthreads();
    for (int i = 0; i < 4; i++) {
        int n = n0 + ty + 16 * i;
        bf16x4 o;
        o[0] = tile[ty + 16 * i][tx * 4 + 0];
        o[1] = tile[ty + 16 * i][tx * 4 + 1];
        o[2] = tile[ty + 16 * i][tx * 4 + 2];
        o[3] = tile[ty + 16 * i][tx * 4 + 3];
        *(bf16x4*)(dst + (size_t)n * K + k0 + tx * 4) = o;
    }
}

// ---------------------------------------------------------------------------
// GEMM1: H = leaky_relu(A1 @ W1 + b1), emitted in Apack fragment-major
// layout.  128x128 tile, 4 waves (2x2), 16x16x32 MFMA, BK=32.  Epilogue
// round-trips C through LDS so the Apack stores are fully coalesced.
// ---------------------------------------------------------------------------
__global__ __launch_bounds__(256) void gemm1_kernel(
        const __bf16* __restrict__ A, const __bf16* __restrict__ Bt,
        const float* __restrict__ bias, __bf16* __restrict__ Apack, int K) {
    __shared__ __align__(16) __bf16 At[128][40];
    __shared__ __align__(16) __bf16 Bl[128][40];
    __shared__ __align__(16) __bf16 Cld[128][136];
    const int t = threadIdx.x;
    const int by = blockIdx.y, bx = blockIdx.x;
    const int m0 = by * 128, n0 = bx * 128;
    const int srow = t >> 2, schunk = (t & 3) * 8;
    const int wave = t >> 6, lane = t & 63;
    const int wrow = (wave >> 1) * 64, wcol = (wave & 1) * 64;
    const int q = lane >> 4, ln = lane & 15;

    f32x4 acc[4][4] = {};
    for (int k0 = 0; k0 < K; k0 += 32) {
        __syncthreads();
        *(bf16x8*)&At[srow][schunk]      = *(const bf16x8*)(A  + (size_t)(m0 + srow)      * K + k0 + schunk);
        *(bf16x8*)&At[srow + 64][schunk] = *(const bf16x8*)(A  + (size_t)(m0 + srow + 64) * K + k0 + schunk);
        *(bf16x8*)&Bl[srow][schunk]      = *(const bf16x8*)(Bt + (size_t)(n0 + srow)      * K + k0 + schunk);
        *(bf16x8*)&Bl[srow + 64][schunk] = *(const bf16x8*)(Bt + (size_t)(n0 + srow + 64) * K + k0 + schunk);
        __syncthreads();
        bf16x8 af[4], bfr[4];
        for (int i = 0; i < 4; i++) af[i]  = *(const bf16x8*)&At[wrow + i * 16 + ln][q * 8];
        for (int i = 0; i < 4; i++) bfr[i] = *(const bf16x8*)&Bl[wcol + i * 16 + ln][q * 8];
        for (int mi = 0; mi < 4; mi++)
            for (int ni = 0; ni < 4; ni++)
                acc[mi][ni] = MFMA16(af[mi], bfr[ni], acc[mi][ni]);
    }
    // bias + leaky -> LDS C tile
    for (int ni = 0; ni < 4; ni++) {
        int gcol = n0 + wcol + ni * 16 + ln;
        float bv = bias[gcol];
        for (int mi = 0; mi < 4; mi++)
            for (int r = 0; r < 4; r++) {
                float v = acc[mi][ni][r] + bv;
                v = v > 0.0f ? v : 0.01f * v;
                Cld[wrow + mi * 16 + q * 4 + r][wcol + ni * 16 + ln] = (__bf16)v;
            }
    }
    __syncthreads();
    // pack out: 32 chunks (pl 0..1, ksl 0..3, mi 0..3), wave w -> c = w+4i
    for (int i = 0; i < 8; i++) {
        int c   = wave + 4 * i;
        int pl  = c >> 4, ksl = (c >> 2) & 3, mi = c & 3;
        int row = pl * 64 + mi * 16 + (lane & 15);
        int col = ksl * 32 + (lane >> 4) * 8;
        bf16x8 v = *(const bf16x8*)&Cld[row][col];
        size_t base = apack_chunk(2 * by + pl, 4 * bx + ksl, mi);
        *(bf16x8*)(Apack + base + lane * 8) = v;
    }
}

// ---------------------------------------------------------------------------
// GEMM2 (persistent 64-col strip, 512 threads = 8 waves, 2 blocks/CU):
// stage W2 strip fp32->bf16 into LDS ONCE in fragment-major "Bpack" layout
// (chunk (ks*4+ni) = 1 KB, lane l at +16B*l -> conflict-free b128 reads;
// non-temporal global loads so the 131 MB stream doesn't evict Apack from
// L2).  Each wave sweeps 64-row panels reading Apack as coalesced 16 B/lane
// streams with one-k-step prefetch.  Epilogue: exp-rowsum -> shuffle reduce
// -> coalesced per-strip partial store; label logit via labcol compare.
// ---------------------------------------------------------------------------
__global__ __launch_bounds__(512, 4) void gemm2_kernel(
        const __bf16* __restrict__ Apack, const float* __restrict__ w2,
        const float* __restrict__ b2, const int* __restrict__ labcol,
        float* __restrict__ partial, float* __restrict__ lab, int Mpad) {
    __shared__ __align__(16) __bf16 Bp[64 * 512];   // 64 KB, fragment-major
    const int t = threadIdx.x;
    const int strip = blockIdx.x;
    const int c0 = strip * 64;
    const int branch = (c0 >= V) ? 1 : 0;

    // ---- stage W2 strip fp32 [512][64000] -> Bpack bf16
    {
        const int col = t & 63;
        const int ni = col >> 4, lncol = col & 15;
        const int kb0 = (t >> 6) * 8;
        for (int r = 0; r < 8; r++) {
            int kb = kb0 + r * 64;
            int ks = kb >> 5, qk = (kb >> 3) & 3;
            float v[8];
#pragma unroll
            for (int j = 0; j < 8; j++)
                v[j] = __builtin_nontemporal_load(w2 + (size_t)(kb + j) * N2 + c0 + col);
            bf16x8 o;
#pragma unroll
            for (int j = 0; j < 8; j++) o[j] = (__bf16)v[j];
            *(bf16x8*)&Bp[(size_t)(((ks * 4 + ni) * 64 + qk * 16 + lncol)) * 8] = o;
        }
    }
    __syncthreads();

    const int wave = t >> 6, lane = t & 63;
    const int q = lane >> 4, ln = lane & 15;

    float bvn[4];
#pragma unroll
    for (int ni = 0; ni < 4; ni++) bvn[ni] = b2[c0 + ni * 16 + ln];

    const int npanels = Mpad >> 6;
    for (int p = wave; p < npanels; p += 8) {
        const __bf16* base = Apack + apack_chunk(p, 0, 0) + lane * 8;

        f32x4 acc[4][4] = {};
        bf16x8 afc[4], afn[4];
#pragma unroll
        for (int mi = 0; mi < 4; mi++)
            afc[mi] = *(const bf16x8*)(base + mi * 512);
#pragma unroll 1
        for (int ks = 0; ks < 16; ks++) {
            if (ks < 15) {
#pragma unroll
                for (int mi = 0; mi < 4; mi++)
                    afn[mi] = *(const bf16x8*)(base + (size_t)(ks + 1) * 2048 + mi * 512);
            }
            bf16x8 bf[4];
#pragma unroll
            for (int ni = 0; ni < 4; ni++)
                bf[ni] = *(const bf16x8*)&Bp[(size_t)(ks * 4 + ni) * 512 + lane * 8];
#pragma unroll
            for (int mi = 0; mi < 4; mi++)
#pragma unroll
                for (int ni = 0; ni < 4; ni++)
                    acc[mi][ni] = MFMA16(afc[mi], bf[ni], acc[mi][ni]);
#pragma unroll
            for (int mi = 0; mi < 4; mi++) afc[mi] = afn[mi];
        }

        // ---- epilogue for this panel
        int lc[4][4];
#pragma unroll
        for (int mi = 0; mi < 4; mi++)
#pragma unroll
            for (int r = 0; r < 4; r++)
                lc[mi][r] = labcol[(p * 64 + mi * 16 + q * 4 + r) * 2 + branch];

        float rowsum[4][4];
#pragma unroll
        for (int mi = 0; mi < 4; mi++)
#pragma unroll
            for (int r = 0; r < 4; r++) rowsum[mi][r] = 0.0f;

#pragma unroll
        for (int ni = 0; ni < 4; ni++) {
            const int gcol = c0 + ni * 16 + ln;
            const float bv = bvn[ni];
#pragma unroll
            for (int mi = 0; mi < 4; mi++)
#pragma unroll
                for (int r = 0; r < 4; r++) {
                    float v = acc[mi][ni][r] + bv;
                    rowsum[mi][r] += __expf(v);
                    if (gcol == lc[mi][r]) {
                        int gm = p * 64 + mi * 16 + q * 4 + r;
                        lab[gm * 2 + branch] = v;
                    }
                }
        }
        // reduce over the 16 column-lanes (lane bits 0..3)
#pragma unroll
        for (int mi = 0; mi < 4; mi++)
#pragma unroll
            for (int r = 0; r < 4; r++) {
                float s = rowsum[mi][r];
                s += __shfl_xor(s, 1);
                s += __shfl_xor(s, 2);
                s += __shfl_xor(s, 4);
                s += __shfl_xor(s, 8);
                rowsum[mi][r] = s;
            }
        // per-lane row gather: lane l wants row l = mi*16 + q*4 + r; value
        // lives in lanes with q-src = (l>>2)&3 at register rowsum[l>>4][l&3].
        float mine = 0.0f;
        const int srcl = ((lane >> 2) & 3) * 16;
#pragma unroll
        for (int mi2 = 0; mi2 < 4; mi2++)
#pragma unroll
            for (int r2 = 0; r2 < 4; r2++) {
                float tv = __shfl(rowsum[mi2][r2], srcl);
                if ((lane >> 4) == mi2 && (lane & 3) == r2) mine = tv;
            }
        partial[(size_t)strip * Mpad + p * 64 + lane] = mine;
    }
}

// ---------------------------------------------------------------------------
// Reduce partials: sumexp[m*2+br] = sum over the branch's 500 strips.
// ---------------------------------------------------------------------------
__global__ void reduce_sumexp_kernel(const float* __restrict__ partial,
                                     float* __restrict__ sumexp, int Mpad) {
    int t = blockIdx.x * 256 + threadIdx.x;
    if (t >= Mpad * 2) return;
    int br = t / Mpad, m = t - br * Mpad;
    int s0 = br * (NSTRIP / 2), s1 = s0 + NSTRIP / 2;
    float s = 0.0f;
#pragma unroll 4
    for (int si = s0; si < s1; si++)
        s += partial[(size_t)si * Mpad + m];
    sumexp[m * 2 + br] = s;
}

// ---------------------------------------------------------------------------
// Final reduce: out = mean over (m, branch) of weight[branch] * nll,
// nll = log(sumexp) - label_logit, weights (1.0, 0.25).
// ---------------------------------------------------------------------------
__global__ void final_reduce_kernel(const float* __restrict__ sumexp,
                                    const float* __restrict__ lab,
                                    float* __restrict__ out, int M) {
    __shared__ float red[4];
    float acc = 0.0f;
    for (int m = threadIdx.x; m < M; m += 256) {
        float nf = logf(sumexp[m * 2 + 0]) - lab[m * 2 + 0];
        float nb = logf(sumexp[m * 2 + 1]) - lab[m * 2 + 1];
        acc += nf + 0.25f * nb;
    }
    acc += __shfl_xor(acc, 32);
    acc += __shfl_xor(acc, 16);
    acc += __shfl_xor(acc, 8);
    acc += __shfl_xor(acc, 4);
    acc += __shfl_xor(acc, 2);
    acc += __shfl_xor(acc, 1);
    int wv = threadIdx.x >> 6, ln = threadIdx.x & 63;
    if (ln == 0) red[wv] = acc;
    __syncthreads();
    if (threadIdx.x == 0)
        out[0] = (red[0] + red[1] + red[2] + red[3]) / (float)(2 * M);
}

// ---------------------------------------------------------------------------
extern "C" void kernel_launch(void* const* d_in, const int* in_sizes, int n_in,
                              void* d_out, int out_size, void* d_ws, size_t ws_size,
                              hipStream_t stream) {
    const float* fwd = (const float*)d_in[0];
    const float* bwd = (const float*)d_in[1];
    const int*   seq = (const int*)d_in[2];
    const int*   fi  = (const int*)d_in[3];
    const int*   bi  = (const int*)d_in[4];
    const float* w1  = (const float*)d_in[5];
    const float* b1  = (const float*)d_in[6];
    const float* w2  = (const float*)d_in[7];
    const float* b2  = (const float*)d_in[8];
    float* out = (float*)d_out;

    const int N    = in_sizes[3];              // 1303
    const int M    = Bsz * N;                  // 2606
    const int Mpad = ((M + 255) / 256) * 256;  // 2816

    // workspace layout (16B-aligned slices)
    char* ws = (char*)d_ws;
    __bf16* A1    = (__bf16*)(ws);                                   // Mpad*1024
    __bf16* W1T   = (__bf16*)(ws + (size_t)Mpad * K1 * 2);           // 512*1024
    __bf16* Apack = (__bf16*)((char*)W1T + (size_t)N1 * K1 * 2);     // Mpad*512
    float*  partial = (float*)((char*)Apack + (size_t)Mpad * N1 * 2);// NSTRIP*Mpad
    float*  sumexp  = (float*)((char*)partial + (size_t)NSTRIP * Mpad * 4); // Mpad*2
    float*  lab     = (float*)((char*)sumexp + (size_t)Mpad * 2 * 4);// Mpad*2
    int*    labcol  = (int*)((char*)lab + (size_t)Mpad * 2 * 4);     // Mpad*2

    // 1. gather + cast (zero-fills pad rows) + labcol side-task
    {
        int total = Mpad * (K1 / 8);
        gather_cast_kernel<<<(total + 255) / 256, 256, 0, stream>>>(
            fwd, bwd, fi, bi, seq, A1, labcol, N, M, Mpad);
    }
    // 2. transpose+cast w1
    transpose_cast_kernel<<<dim3(N1 / 64, K1 / 64), 256, 0, stream>>>(w1, W1T, K1, N1);
    // 3. GEMM1 -> Apack (fragment-major H)
    gemm1_kernel<<<dim3(N1 / 128, Mpad / 128), 256, 0, stream>>>(A1, W1T, b1, Apack, K1);
    // 4. GEMM2 persistent strips -> per-strip partial rowsums + labels
    gemm2_kernel<<<NSTRIP, 512, 0, stream>>>(Apack, w2, b2, labcol, partial, lab, Mpad);
    // 5. reduce partials -> sumexp
    reduce_sumexp_kernel<<<(Mpad * 2 + 255) / 256, 256, 0, stream>>>(partial, sumexp, Mpad);
    // 6. final scalar
    final_reduce_kernel<<<1, 256, 0, stream>>>(sumexp, lab, out, M);
}